// Round 7
// baseline (193.417 us; speedup 1.0000x reference)
//
#include <hip/hip_runtime.h>
#include <stdint.h>

typedef __attribute__((ext_vector_type(8))) short short8;
typedef __attribute__((ext_vector_type(8))) unsigned short ushort8;
typedef __attribute__((ext_vector_type(4))) float floatx4;

#define W_DIM 900
#define NPAD  450
#define LDST  40          // LDS row stride in bf16 elems: 80 B, 16B-aligned, 2-way banks
#define BOFF  5120        // B region offset in elems (128*40)

__device__ __forceinline__ unsigned short f2bf(float f) {
  unsigned int u = __builtin_bit_cast(unsigned int, f);
  return (unsigned short)((u + 0x8000u) >> 16);   // round-half-up (r3-proven)
}

// ---------------------------------------------------------------------------
// Fused: fp32 [b,h,w,c] -> bf16 LDS tiles -> gram GEMM -> circular-band sum.
// out[b,s] = sum over diag i-j-450 = s (mod 900) of <x1_i, x2_j>, D=1024.
//
// Tile 128x128, BK=32. Grid 1024 = (it*8+jt)*16 + b  (x%8 = b%8 -> one
// batch-group per XCD, fp32 re-reads are L2 hits). 4 waves; wave (wm,wn) owns
// a 64x64 quadrant via 4x4 frags of mfma 16x16x32_bf16 (acc = 64 VGPR ->
// 3 waves/SIMD with launch_bounds(256,3); r3's 128-reg acc capped at 2).
// Pipeline (r3-proven order): loads kt+1 issued before MFMA(kt).
// ---------------------------------------------------------------------------
__global__ __launch_bounds__(256, 3)
void fused_gram_band(const float* __restrict__ X1, const float* __restrict__ X2,
                     float* __restrict__ out) {
  const int x    = blockIdx.x;
  const int b    = x & 15;
  const int pair = x >> 4;
  const int it   = pair >> 3;          // 0..7
  const int jt   = pair & 7;           // 0..7

  __shared__ __align__(16) unsigned char smem[20480];
  unsigned short* As = (unsigned short*)smem;   // [128][40]; B at +BOFF [128][40]

  const int tid  = threadIdx.x;
  const int lane = tid & 63;
  const int warp = tid >> 6;
  const int wm   = warp >> 1;
  const int wn   = warp & 1;

  // Staging: warp stages A rows [warp*32, +32) and B rows [warp*32, +32).
  // Quarter-wave per row: lane -> row sub rsub, 8-float chunk c8.
  const int rsub = lane >> 2;
  const int c8   = (lane & 3) << 3;

  int arl[2], brl[2];
  bool aok[2], bok[2];
#pragma unroll
  for (int g = 0; g < 2; ++g) {
    arl[g] = it * 128 + warp * 32 + g * 16 + rsub;   // global w row of A
    aok[g] = arl[g] < W_DIM;
    brl[g] = jt * 128 + warp * 32 + g * 16 + rsub;
    bok[g] = brl[g] < W_DIM;
  }
  const size_t bbase = (size_t)b * 4 * W_DIM * 256;

  float4 va[2][2], vb[2][2];
  const float4 fz = make_float4(0.f, 0.f, 0.f, 0.f);

#define LOAD_SLAB(kt)                                                          \
  {                                                                            \
    const size_t koff = bbase + (size_t)((kt) >> 3) * (W_DIM * 256) +          \
                        ((kt) & 7) * 32 + c8;                                  \
    _Pragma("unroll")                                                          \
    for (int g = 0; g < 2; ++g) {                                              \
      va[g][0] = fz; va[g][1] = fz; vb[g][0] = fz; vb[g][1] = fz;              \
      if (aok[g]) {                                                            \
        const float* p = X1 + koff + (size_t)arl[g] * 256;                     \
        va[g][0] = *(const float4*)p; va[g][1] = *(const float4*)(p + 4);      \
      }                                                                        \
      if (bok[g]) {                                                            \
        const float* p = X2 + koff + (size_t)brl[g] * 256;                     \
        vb[g][0] = *(const float4*)p; vb[g][1] = *(const float4*)(p + 4);      \
      }                                                                        \
    }                                                                          \
  }

  floatx4 acc[4][4];
#pragma unroll
  for (int i = 0; i < 4; ++i)
#pragma unroll
    for (int j = 0; j < 4; ++j) acc[i][j] = (floatx4)0.0f;

  const int quad = lane >> 4;
  const int r16  = lane & 15;
  const unsigned short* ArowBase = As + (wm * 64 + r16) * LDST + quad * 8;
  const unsigned short* BrowBase = As + BOFF + (wn * 64 + r16) * LDST + quad * 8;

  // LDS write targets (16B-aligned: row*80 + (lane&3)*16 bytes).
  unsigned short* lwA[2];
  unsigned short* lwB[2];
#pragma unroll
  for (int g = 0; g < 2; ++g) {
    lwA[g] = As + (warp * 32 + g * 16 + rsub) * LDST + c8;
    lwB[g] = As + BOFF + (warp * 32 + g * 16 + rsub) * LDST + c8;
  }

  LOAD_SLAB(0);

  for (int kt = 0; kt < 32; ++kt) {
    __syncthreads();                   // frag reads of kt-1 complete
#pragma unroll
    for (int g = 0; g < 2; ++g) {
      ushort8 oa, ob;
      oa[0] = f2bf(va[g][0].x); oa[1] = f2bf(va[g][0].y);
      oa[2] = f2bf(va[g][0].z); oa[3] = f2bf(va[g][0].w);
      oa[4] = f2bf(va[g][1].x); oa[5] = f2bf(va[g][1].y);
      oa[6] = f2bf(va[g][1].z); oa[7] = f2bf(va[g][1].w);
      *(ushort8*)lwA[g] = oa;
      ob[0] = f2bf(vb[g][0].x); ob[1] = f2bf(vb[g][0].y);
      ob[2] = f2bf(vb[g][0].z); ob[3] = f2bf(vb[g][0].w);
      ob[4] = f2bf(vb[g][1].x); ob[5] = f2bf(vb[g][1].y);
      ob[6] = f2bf(vb[g][1].z); ob[7] = f2bf(vb[g][1].w);
      *(ushort8*)lwB[g] = ob;
    }
    __syncthreads();                   // writes visible

    if (kt < 31) LOAD_SLAB(kt + 1);    // in flight across MFMA + next barrier

    short8 af[4], bf[4];
#pragma unroll
    for (int mi = 0; mi < 4; ++mi)
      af[mi] = *(const short8*)(ArowBase + mi * 16 * LDST);
#pragma unroll
    for (int ni = 0; ni < 4; ++ni)
      bf[ni] = *(const short8*)(BrowBase + ni * 16 * LDST);
#pragma unroll
    for (int mi = 0; mi < 4; ++mi)
#pragma unroll
      for (int ni = 0; ni < 4; ++ni)
        acc[mi][ni] = __builtin_amdgcn_mfma_f32_16x16x32_bf16(
            af[mi], bf[ni], acc[mi][ni], 0, 0, 0);
  }

  // ---- Epilogue: gram[i,j] -> out[b, (i-j-450) mod 900]; 4 passes, 32 rows.
  __syncthreads();                     // all frag reads done; alias staging
  float* Ep = (float*)smem;            // [32][132] = 16896 B
  const int dbase = it * 128 - jt * 128 - NPAD;

  for (int p = 0; p < 4; ++p) {
    if (wm == (p >> 1)) {
      const int mib = (p & 1) * 2;     // this pass: mi in {mib, mib+1}
#pragma unroll
      for (int mo = 0; mo < 2; ++mo)
#pragma unroll
        for (int ni = 0; ni < 4; ++ni)
#pragma unroll
          for (int rr = 0; rr < 4; ++rr) {
            const int lr = mo * 16 + quad * 4 + rr;       // 0..31 within pass
            const int c  = wn * 64 + ni * 16 + r16;       // 0..127
            Ep[lr * 132 + c] = acc[mib + mo][ni][rr];
          }
    }
    __syncthreads();
    if (tid < 159) {
      // d = i_local - j_local for rows [p*32, p*32+32): d = p*32 - 127 + tid
      const int k0 = tid > 127 ? tid - 127 : 0;
      int k1 = tid + 1; if (k1 > 32) k1 = 32;
      const int joff = 127 - tid;      // j = k + joff
      float s = 0.0f;
      for (int k = k0; k < k1; ++k) s += Ep[k * 132 + k + joff];
      int dg = dbase + p * 32 - 127 + tid;
      int sidx = dg % W_DIM;
      if (sidx < 0) sidx += W_DIM;
      atomicAdd(&out[b * W_DIM + sidx], s);
    }
    __syncthreads();
  }
}

extern "C" void kernel_launch(void* const* d_in, const int* in_sizes, int n_in,
                              void* d_out, int out_size, void* d_ws, size_t ws_size,
                              hipStream_t stream) {
  const float* x1 = (const float*)d_in[0];
  const float* x2 = (const float*)d_in[1];
  float* out = (float*)d_out;

  hipMemsetAsync(d_out, 0, (size_t)out_size * sizeof(float), stream);
  fused_gram_band<<<dim3(1024), 256, 0, stream>>>(x1, x2, out);
}